// Round 5
// baseline (275.085 us; speedup 1.0000x reference)
//
#include <hip/hip_runtime.h>

// GCN: out = Ahat( relu( Ahat(x@W1) + b1 ) @ W2 ) + b2,  Ahat = D^-1/2 (A+I) D^-1/2
// N=10000, E=640000, IN=128, HID=128, OUT=64.
// Strategy: dinv[dst] factors out of the message sum, so aggregation is a pure
// gather: agg[n] = dinv[n] * ( hs[n] + sum_{e in in(n)} hs[src_e] ), where
// hs = (x@W) * dinv[src] from the GEMM epilogue. CSR (by dst) is built on
// device each call; aggregation does register accumulation + one store per
// node — no f32 atomics in the hot path.

static constexpr int IN_F  = 128;
static constexpr int HID_F = 128;
static constexpr int OUT_F = 64;

__global__ void zero_deg_k(int* __restrict__ deg, int N) {
  int i = blockIdx.x * blockDim.x + threadIdx.x;
  if (i < N) deg[i] = 0;
}

__global__ void count_deg_k(const int* __restrict__ dst, int* __restrict__ deg, int E) {
  int i = blockIdx.x * blockDim.x + threadIdx.x;
  if (i < E) atomicAdd(&deg[dst[i]], 1);
}

// Single-block exclusive scan of deg[0..N) -> row_start[0..N], plus cursor copy
// and dinv = 1/sqrt(deg+1) (self-loop included in degree, so always >= 1).
__global__ __launch_bounds__(1024) void scan_dinv_k(
    const int* __restrict__ deg, int* __restrict__ row_start,
    int* __restrict__ cursor, float* __restrict__ dinv, int N) {
  __shared__ int partial[1024];
  const int t  = threadIdx.x;
  const int CH = (N + 1023) / 1024;       // elements per thread
  int local[16];                           // CH <= 16 supported
  int sum = 0;
  for (int i = 0; i < CH; ++i) {
    int idx = t * CH + i;
    int v = (idx < N) ? deg[idx] : 0;
    local[i] = sum;                        // exclusive within chunk
    sum += v;
  }
  partial[t] = sum;
  __syncthreads();
  // Hillis-Steele inclusive scan over the 1024 partials
  for (int off = 1; off < 1024; off <<= 1) {
    int v = (t >= off) ? partial[t - off] : 0;
    __syncthreads();
    partial[t] += v;
    __syncthreads();
  }
  const int prev = (t == 0) ? 0 : partial[t - 1];
  for (int i = 0; i < CH; ++i) {
    int idx = t * CH + i;
    if (idx < N) {
      int rs = prev + local[i];
      row_start[idx] = rs;
      cursor[idx]    = rs;
      dinv[idx]      = 1.0f / sqrtf((float)(deg[idx] + 1));
    }
  }
  if (t == 0) row_start[N] = partial[1023];
}

__global__ void fill_csr_k(const int* __restrict__ src, const int* __restrict__ dst,
                           int* __restrict__ cursor, int* __restrict__ csr_src, int E) {
  int e = blockIdx.x * blockDim.x + threadIdx.x;
  if (e < E) {
    int pos = atomicAdd(&cursor[dst[e]], 1);
    csr_src[pos] = src[e];
  }
}

// hs[n][f] = (sum_k in'[n][k] * W[k][f]) * dinv[n]   (pre-scaled by src side)
// in'[n][k] = RELU_BIAS ? relu(in[n][k] + bin[k]) : in[n][k]
template<int K, int F, int NB, bool RELU_BIAS>
__global__ __launch_bounds__(F) void gemm_scale_k(
    const float* __restrict__ in, const float* __restrict__ W,
    const float* __restrict__ bin, const float* __restrict__ dinv,
    float* __restrict__ hs, int N) {
  __shared__ float xs[NB][K];
  const int f  = threadIdx.x;
  const int n0 = blockIdx.x * NB;

  for (int i = 0; i < NB; ++i) {
    int n = n0 + i;
    for (int k = f; k < K; k += F) {
      float v = (n < N) ? in[(long)n * K + k] : 0.0f;
      if (RELU_BIAS) v = fmaxf(v + bin[k], 0.0f);
      xs[i][k] = v;
    }
  }
  __syncthreads();

  float acc[NB];
#pragma unroll
  for (int i = 0; i < NB; ++i) acc[i] = 0.0f;

  for (int k = 0; k < K; ++k) {
    float w = W[k * F + f];
#pragma unroll
    for (int i = 0; i < NB; ++i) acc[i] = fmaf(xs[i][k], w, acc[i]);
  }

  for (int i = 0; i < NB; ++i) {
    int n = n0 + i;
    if (n < N) hs[(long)n * F + f] = acc[i] * dinv[n];
  }
}

// One wave per node: out[n] = dinv[n] * (hs[n] + sum_{in-edges} hs[src]) [+ bias]
template<int F, bool ADD_BIAS>
__global__ __launch_bounds__(256) void gather_agg_k(
    const int* __restrict__ row_start, const int* __restrict__ csr_src,
    const float* __restrict__ dinv, const float* __restrict__ hs,
    const float* __restrict__ bias, float* __restrict__ out, int N) {
  const int wid  = (int)((blockIdx.x * blockDim.x + threadIdx.x) >> 6);
  const int lane = threadIdx.x & 63;
  if (wid >= N) return;
  const int n   = wid;
  const int beg = row_start[n];
  const int end = row_start[n + 1];

  float ax, ay;
  if (F == 128) {
    const float2 v = *reinterpret_cast<const float2*>(hs + (long)n * 128 + lane * 2);
    ax = v.x; ay = v.y;
  } else {
    ax = hs[(long)n * 64 + lane]; ay = 0.0f;
  }

  for (int i = beg; i < end; i += 64) {
    const int cnt = min(64, end - i);
    const int sidx = (lane < cnt) ? csr_src[i + lane] : 0;
#pragma unroll 4
    for (int j = 0; j < cnt; ++j) {
      const int s = __shfl(sidx, j);
      if (F == 128) {
        const float2 v = *reinterpret_cast<const float2*>(hs + (long)s * 128 + lane * 2);
        ax += v.x; ay += v.y;
      } else {
        ax += hs[(long)s * 64 + lane];
      }
    }
  }

  const float di = dinv[n];
  if (F == 128) {
    float2 r; r.x = ax * di; r.y = ay * di;
    *reinterpret_cast<float2*>(out + (long)n * 128 + lane * 2) = r;
  } else {
    float v = ax * di;
    if (ADD_BIAS) v += bias[lane];
    out[(long)n * 64 + lane] = v;
  }
}

extern "C" void kernel_launch(void* const* d_in, const int* in_sizes, int n_in,
                              void* d_out, int out_size, void* d_ws, size_t ws_size,
                              hipStream_t stream) {
  const float* x  = (const float*)d_in[0];
  const float* W1 = (const float*)d_in[1];
  const float* b1 = (const float*)d_in[2];
  const float* W2 = (const float*)d_in[3];
  const float* b2 = (const float*)d_in[4];
  const int*   ei = (const int*)d_in[5];

  const int N = in_sizes[0] / IN_F;
  const int E = in_sizes[5] / 2;
  const int* src = ei;        // edge_index[0]
  const int* dst = ei + E;    // edge_index[1]
  float* out = (float*)d_out; // [N, 64]

  // workspace layout
  const int Npad = (N + 256) & ~255;
  int*   deg       = (int*)d_ws;                     // N
  int*   row_start = deg + Npad;                     // N+1
  int*   cursor    = row_start + Npad;               // N
  int*   csr_src   = cursor + Npad;                  // E
  float* dinv      = (float*)(csr_src + ((E + 255) & ~255)); // N
  float* hs1       = dinv + Npad;                    // N*128
  float* agg1      = hs1 + (size_t)N * HID_F;        // N*128
  float* hs2       = hs1;                            // reuse: hs1 dead after layer-1 gather

  const int B = 256;
  constexpr int NB = 8;

  // ---- CSR build (shared by both layers) ----
  zero_deg_k<<<(N + B - 1) / B, B, 0, stream>>>(deg, N);
  count_deg_k<<<(E + B - 1) / B, B, 0, stream>>>(dst, deg, E);
  scan_dinv_k<<<1, 1024, 0, stream>>>(deg, row_start, cursor, dinv, N);
  fill_csr_k<<<(E + B - 1) / B, B, 0, stream>>>(src, dst, cursor, csr_src, E);

  // ---- layer 1 ----
  gemm_scale_k<IN_F, HID_F, NB, false>
      <<<(N + NB - 1) / NB, HID_F, 0, stream>>>(x, W1, nullptr, dinv, hs1, N);
  gather_agg_k<HID_F, false>
      <<<((size_t)N * 64 + B - 1) / B, B, 0, stream>>>(row_start, csr_src, dinv, hs1,
                                                       nullptr, agg1, N);

  // ---- layer 2 (bias b1 + relu folded into GEMM load; b2 folded into store) ----
  gemm_scale_k<HID_F, OUT_F, NB, true>
      <<<(N + NB - 1) / NB, OUT_F, 0, stream>>>(agg1, W2, b1, dinv, hs2, N);
  gather_agg_k<OUT_F, true>
      <<<((size_t)N * 64 + B - 1) / B, B, 0, stream>>>(row_start, csr_src, dinv, hs2,
                                                       b2, out, N);
}

// Round 9
// 236.153 us; speedup vs baseline: 1.1649x; 1.1649x over previous
//
#include <hip/hip_runtime.h>

// GCN: out = Ahat( relu( Ahat(x@W1) + b1 ) @ W2 ) + b2,  Ahat = D^-1/2 (A+I) D^-1/2
// N=10000, E=640000, IN=128, HID=128, OUT=64.
// CSR-by-dst gather formulation (round 3) + 8-deep MLP batching in the gather
// inner loop (round 5): the gather was latency-bound (VALUBusy 14%, HBM 13%,
// VGPR=12 -> ~2 loads in flight). Batch 8 independent edge gathers into
// registers before the add tree; edge indices read via wave-uniform scalar path.

static constexpr int IN_F  = 128;
static constexpr int HID_F = 128;
static constexpr int OUT_F = 64;

__global__ void zero_deg_k(int* __restrict__ deg, int N) {
  int i = blockIdx.x * blockDim.x + threadIdx.x;
  if (i < N) deg[i] = 0;
}

__global__ void count_deg_k(const int* __restrict__ dst, int* __restrict__ deg, int E) {
  int i = blockIdx.x * blockDim.x + threadIdx.x;
  if (i < E) atomicAdd(&deg[dst[i]], 1);
}

// Single-block exclusive scan of deg[0..N) -> row_start[0..N], plus cursor copy
// and dinv = 1/sqrt(deg+1) (self-loop included, so always >= 1).
__global__ __launch_bounds__(1024) void scan_dinv_k(
    const int* __restrict__ deg, int* __restrict__ row_start,
    int* __restrict__ cursor, float* __restrict__ dinv, int N) {
  __shared__ int partial[1024];
  const int t  = threadIdx.x;
  const int CH = (N + 1023) / 1024;       // elements per thread
  int local[16];                           // CH <= 16 supported
  int sum = 0;
  for (int i = 0; i < CH; ++i) {
    int idx = t * CH + i;
    int v = (idx < N) ? deg[idx] : 0;
    local[i] = sum;                        // exclusive within chunk
    sum += v;
  }
  partial[t] = sum;
  __syncthreads();
  for (int off = 1; off < 1024; off <<= 1) {
    int v = (t >= off) ? partial[t - off] : 0;
    __syncthreads();
    partial[t] += v;
    __syncthreads();
  }
  const int prev = (t == 0) ? 0 : partial[t - 1];
  for (int i = 0; i < CH; ++i) {
    int idx = t * CH + i;
    if (idx < N) {
      int rs = prev + local[i];
      row_start[idx] = rs;
      cursor[idx]    = rs;
      dinv[idx]      = 1.0f / sqrtf((float)(deg[idx] + 1));
    }
  }
  if (t == 0) row_start[N] = partial[1023];
}

__global__ void fill_csr_k(const int* __restrict__ src, const int* __restrict__ dst,
                           int* __restrict__ cursor, int* __restrict__ csr_src, int E) {
  int e = blockIdx.x * blockDim.x + threadIdx.x;
  if (e < E) {
    int pos = atomicAdd(&cursor[dst[e]], 1);
    csr_src[pos] = src[e];
  }
}

// hs[n][f] = (sum_k in'[n][k] * W[k][f]) * dinv[n]   (pre-scaled by src side)
// in'[n][k] = RELU_BIAS ? relu(in[n][k] + bin[k]) : in[n][k]
template<int K, int F, int NB, bool RELU_BIAS>
__global__ __launch_bounds__(F) void gemm_scale_k(
    const float* __restrict__ in, const float* __restrict__ W,
    const float* __restrict__ bin, const float* __restrict__ dinv,
    float* __restrict__ hs, int N) {
  __shared__ float xs[NB][K];
  const int f  = threadIdx.x;
  const int n0 = blockIdx.x * NB;

  for (int i = 0; i < NB; ++i) {
    int n = n0 + i;
    for (int k = f; k < K; k += F) {
      float v = (n < N) ? in[(long)n * K + k] : 0.0f;
      if (RELU_BIAS) v = fmaxf(v + bin[k], 0.0f);
      xs[i][k] = v;
    }
  }
  __syncthreads();

  float acc[NB];
#pragma unroll
  for (int i = 0; i < NB; ++i) acc[i] = 0.0f;

  for (int k = 0; k < K; ++k) {
    float w = W[k * F + f];
#pragma unroll
    for (int i = 0; i < NB; ++i) acc[i] = fmaf(xs[i][k], w, acc[i]);
  }

  for (int i = 0; i < NB; ++i) {
    int n = n0 + i;
    if (n < N) hs[(long)n * F + f] = acc[i] * dinv[n];
  }
}

// One wave per node: out[n] = dinv[n] * (hs[n] + sum_{in-edges} hs[src]) [+ bias]
// Inner loop batches 8 independent edge gathers (MLP) before a pairwise add tree.
template<int F, bool ADD_BIAS>
__global__ __launch_bounds__(256) void gather_agg_k(
    const int* __restrict__ row_start, const int* __restrict__ csr_src,
    const float* __restrict__ dinv, const float* __restrict__ hs,
    const float* __restrict__ bias, float* __restrict__ out, int N) {
  const int wid  = (int)((blockIdx.x * blockDim.x + threadIdx.x) >> 6);
  const int lane = threadIdx.x & 63;
  if (wid >= N) return;
  // wave-uniform row bounds on the scalar path
  const int beg = __builtin_amdgcn_readfirstlane(row_start[wid]);
  const int end = __builtin_amdgcn_readfirstlane(row_start[wid + 1]);

  float ax, ay;
  if (F == 128) {
    const float2 v = *reinterpret_cast<const float2*>(hs + (long)wid * 128 + lane * 2);
    ax = v.x; ay = v.y;
  } else {
    ax = hs[(long)wid * 64 + lane]; ay = 0.0f;
  }

  int j = beg;
  for (; j + 8 <= end; j += 8) {
    if (F == 128) {
      float2 v0, v1, v2, v3, v4, v5, v6, v7;
      {
        // uniform-address index loads (scalarizable), then 8 independent gathers
        const int s0 = csr_src[j + 0], s1 = csr_src[j + 1];
        const int s2 = csr_src[j + 2], s3 = csr_src[j + 3];
        const int s4 = csr_src[j + 4], s5 = csr_src[j + 5];
        const int s6 = csr_src[j + 6], s7 = csr_src[j + 7];
        const long o = lane * 2;
        v0 = *reinterpret_cast<const float2*>(hs + (long)s0 * 128 + o);
        v1 = *reinterpret_cast<const float2*>(hs + (long)s1 * 128 + o);
        v2 = *reinterpret_cast<const float2*>(hs + (long)s2 * 128 + o);
        v3 = *reinterpret_cast<const float2*>(hs + (long)s3 * 128 + o);
        v4 = *reinterpret_cast<const float2*>(hs + (long)s4 * 128 + o);
        v5 = *reinterpret_cast<const float2*>(hs + (long)s5 * 128 + o);
        v6 = *reinterpret_cast<const float2*>(hs + (long)s6 * 128 + o);
        v7 = *reinterpret_cast<const float2*>(hs + (long)s7 * 128 + o);
      }
      ax += ((v0.x + v1.x) + (v2.x + v3.x)) + ((v4.x + v5.x) + (v6.x + v7.x));
      ay += ((v0.y + v1.y) + (v2.y + v3.y)) + ((v4.y + v5.y) + (v6.y + v7.y));
    } else {
      const int s0 = csr_src[j + 0], s1 = csr_src[j + 1];
      const int s2 = csr_src[j + 2], s3 = csr_src[j + 3];
      const int s4 = csr_src[j + 4], s5 = csr_src[j + 5];
      const int s6 = csr_src[j + 6], s7 = csr_src[j + 7];
      const float v0 = hs[(long)s0 * 64 + lane];
      const float v1 = hs[(long)s1 * 64 + lane];
      const float v2 = hs[(long)s2 * 64 + lane];
      const float v3 = hs[(long)s3 * 64 + lane];
      const float v4 = hs[(long)s4 * 64 + lane];
      const float v5 = hs[(long)s5 * 64 + lane];
      const float v6 = hs[(long)s6 * 64 + lane];
      const float v7 = hs[(long)s7 * 64 + lane];
      ax += ((v0 + v1) + (v2 + v3)) + ((v4 + v5) + (v6 + v7));
    }
  }
  for (; j < end; ++j) {
    const int s = csr_src[j];
    if (F == 128) {
      const float2 v = *reinterpret_cast<const float2*>(hs + (long)s * 128 + lane * 2);
      ax += v.x; ay += v.y;
    } else {
      ax += hs[(long)s * 64 + lane];
    }
  }

  const float di = dinv[wid];
  if (F == 128) {
    float2 r; r.x = ax * di; r.y = ay * di;
    *reinterpret_cast<float2*>(out + (long)wid * 128 + lane * 2) = r;
  } else {
    float v = ax * di;
    if (ADD_BIAS) v += bias[lane];
    out[(long)wid * 64 + lane] = v;
  }
}

extern "C" void kernel_launch(void* const* d_in, const int* in_sizes, int n_in,
                              void* d_out, int out_size, void* d_ws, size_t ws_size,
                              hipStream_t stream) {
  const float* x  = (const float*)d_in[0];
  const float* W1 = (const float*)d_in[1];
  const float* b1 = (const float*)d_in[2];
  const float* W2 = (const float*)d_in[3];
  const float* b2 = (const float*)d_in[4];
  const int*   ei = (const int*)d_in[5];

  const int N = in_sizes[0] / IN_F;
  const int E = in_sizes[5] / 2;
  const int* src = ei;        // edge_index[0]
  const int* dst = ei + E;    // edge_index[1]
  float* out = (float*)d_out; // [N, 64]

  // workspace layout
  const int Npad = (N + 256) & ~255;
  int*   deg       = (int*)d_ws;                     // N
  int*   row_start = deg + Npad;                     // N+1
  int*   cursor    = row_start + Npad;               // N
  int*   csr_src   = cursor + Npad;                  // E
  float* dinv      = (float*)(csr_src + ((E + 255) & ~255)); // N
  float* hs1       = dinv + Npad;                    // N*128
  float* agg1      = hs1 + (size_t)N * HID_F;        // N*128
  float* hs2       = hs1;                            // reuse: hs1 dead after layer-1 gather

  const int B = 256;
  constexpr int NB = 8;

  // ---- CSR build (shared by both layers) ----
  zero_deg_k<<<(N + B - 1) / B, B, 0, stream>>>(deg, N);
  count_deg_k<<<(E + B - 1) / B, B, 0, stream>>>(dst, deg, E);
  scan_dinv_k<<<1, 1024, 0, stream>>>(deg, row_start, cursor, dinv, N);
  fill_csr_k<<<(E + B - 1) / B, B, 0, stream>>>(src, dst, cursor, csr_src, E);

  // ---- layer 1 ----
  gemm_scale_k<IN_F, HID_F, NB, false>
      <<<(N + NB - 1) / NB, HID_F, 0, stream>>>(x, W1, nullptr, dinv, hs1, N);
  gather_agg_k<HID_F, false>
      <<<((size_t)N * 64 + B - 1) / B, B, 0, stream>>>(row_start, csr_src, dinv, hs1,
                                                       nullptr, agg1, N);

  // ---- layer 2 (bias b1 + relu folded into GEMM load; b2 folded into store) ----
  gemm_scale_k<HID_F, OUT_F, NB, true>
      <<<(N + NB - 1) / NB, OUT_F, 0, stream>>>(agg1, W2, b1, dinv, hs2, N);
  gather_agg_k<OUT_F, true>
      <<<((size_t)N * 64 + B - 1) / B, B, 0, stream>>>(row_start, csr_src, dinv, hs2,
                                                       b2, out, N);
}

// Round 11
// 194.099 us; speedup vs baseline: 1.4172x; 1.2167x over previous
//
#include <hip/hip_runtime.h>

// GCN: out = Ahat( relu( Ahat(x@W1) + b1 ) @ W2 ) + b2,  Ahat = D^-1/2 (A+I) D^-1/2
// N=10000, E=640000, IN=128, HID=128, OUT=64.
// r3: CSR gather formulation (no f32 atomics in hot path).
// r5: 8-deep MLP-batched gather (was latency-bound: VALUBusy 14%, VGPR=12).
//     -> gathers dropped out of top-5 (both <44us, from 50us each).
// r9: fill_csr_k measured 44.9us (VALUBusy 0.33% = atomic/scatter latency);
//     count_deg_k pays the same 640k-contended-atomic pattern again.
//     => fixed-slot binning: slots[d*128+pos], pos = atomicAdd(cnt[d]) --
//     eliminates count_deg_k AND scan_dinv_k (no row_start needed); cnt is
//     the degree for dinv. Overflow (P ~ 1e-9, Poisson(64) vs 128 slots)
//     goes to a side list fixed up by a tiny sequential kernel.

static constexpr int IN_F  = 128;
static constexpr int HID_F = 128;
static constexpr int OUT_F = 64;
static constexpr int SLOT  = 128;   // slots per node
static constexpr int OVCAP = 4096;  // overflow list capacity

__global__ void zero_cnt_k(int* __restrict__ cnt, int total) {
  int i = blockIdx.x * blockDim.x + threadIdx.x;
  if (i < total) cnt[i] = 0;   // covers cnt[0..N) and ovf_cnt at cnt[N]
}

// One pass: bin src into dst's slot row; count doubles as degree.
__global__ void fill_slot_k(const int* __restrict__ src, const int* __restrict__ dst,
                            int* __restrict__ cnt, int* __restrict__ slots,
                            int* __restrict__ ovf_cnt, int2* __restrict__ ovf, int E) {
  int e = blockIdx.x * blockDim.x + threadIdx.x;
  if (e < E) {
    int s = src[e], d = dst[e];
    int pos = atomicAdd(&cnt[d], 1);
    if (pos < SLOT) {
      slots[(long)d * SLOT + pos] = s;
    } else {
      int op = atomicAdd(ovf_cnt, 1);
      if (op < OVCAP) ovf[op] = make_int2(s, d);
    }
  }
}

__global__ void dinv_k(const int* __restrict__ cnt, float* __restrict__ dinv, int N) {
  int i = blockIdx.x * blockDim.x + threadIdx.x;
  if (i < N) dinv[i] = 1.0f / sqrtf((float)(cnt[i] + 1));  // +1 self-loop
}

// hs[n][f] = (sum_k in'[n][k] * W[k][f]) * dinv[n]   (pre-scaled by src side)
// in'[n][k] = RELU_BIAS ? relu(in[n][k] + bin[k]) : in[n][k]
template<int K, int F, int NB, bool RELU_BIAS>
__global__ __launch_bounds__(F) void gemm_scale_k(
    const float* __restrict__ in, const float* __restrict__ W,
    const float* __restrict__ bin, const float* __restrict__ dinv,
    float* __restrict__ hs, int N) {
  __shared__ float xs[NB][K];
  const int f  = threadIdx.x;
  const int n0 = blockIdx.x * NB;

  for (int i = 0; i < NB; ++i) {
    int n = n0 + i;
    for (int k = f; k < K; k += F) {
      float v = (n < N) ? in[(long)n * K + k] : 0.0f;
      if (RELU_BIAS) v = fmaxf(v + bin[k], 0.0f);
      xs[i][k] = v;
    }
  }
  __syncthreads();

  float acc[NB];
#pragma unroll
  for (int i = 0; i < NB; ++i) acc[i] = 0.0f;

  for (int k = 0; k < K; ++k) {
    float w = W[k * F + f];
#pragma unroll
    for (int i = 0; i < NB; ++i) acc[i] = fmaf(xs[i][k], w, acc[i]);
  }

  for (int i = 0; i < NB; ++i) {
    int n = n0 + i;
    if (n < N) hs[(long)n * F + f] = acc[i] * dinv[n];
  }
}

// One wave per node: out[n] = dinv[n] * (hs[n] + sum_{slots} hs[src]) [+ bias]
// 8-deep MLP-batched inner loop (r5); slot-row indexing (r9).
template<int F, bool ADD_BIAS>
__global__ __launch_bounds__(256) void gather_slot_k(
    const int* __restrict__ cnt, const int* __restrict__ slots,
    const float* __restrict__ dinv, const float* __restrict__ hs,
    const float* __restrict__ bias, float* __restrict__ out, int N) {
  const int wid  = (int)((blockIdx.x * blockDim.x + threadIdx.x) >> 6);
  const int lane = threadIdx.x & 63;
  if (wid >= N) return;
  const int deg  = __builtin_amdgcn_readfirstlane(min(cnt[wid], SLOT));
  const long base = (long)wid * SLOT;

  float ax, ay;
  if (F == 128) {
    const float2 v = *reinterpret_cast<const float2*>(hs + (long)wid * 128 + lane * 2);
    ax = v.x; ay = v.y;
  } else {
    ax = hs[(long)wid * 64 + lane]; ay = 0.0f;
  }

  int j = 0;
  for (; j + 8 <= deg; j += 8) {
    if (F == 128) {
      float2 v0, v1, v2, v3, v4, v5, v6, v7;
      {
        const int s0 = slots[base + j + 0], s1 = slots[base + j + 1];
        const int s2 = slots[base + j + 2], s3 = slots[base + j + 3];
        const int s4 = slots[base + j + 4], s5 = slots[base + j + 5];
        const int s6 = slots[base + j + 6], s7 = slots[base + j + 7];
        const long o = lane * 2;
        v0 = *reinterpret_cast<const float2*>(hs + (long)s0 * 128 + o);
        v1 = *reinterpret_cast<const float2*>(hs + (long)s1 * 128 + o);
        v2 = *reinterpret_cast<const float2*>(hs + (long)s2 * 128 + o);
        v3 = *reinterpret_cast<const float2*>(hs + (long)s3 * 128 + o);
        v4 = *reinterpret_cast<const float2*>(hs + (long)s4 * 128 + o);
        v5 = *reinterpret_cast<const float2*>(hs + (long)s5 * 128 + o);
        v6 = *reinterpret_cast<const float2*>(hs + (long)s6 * 128 + o);
        v7 = *reinterpret_cast<const float2*>(hs + (long)s7 * 128 + o);
      }
      ax += ((v0.x + v1.x) + (v2.x + v3.x)) + ((v4.x + v5.x) + (v6.x + v7.x));
      ay += ((v0.y + v1.y) + (v2.y + v3.y)) + ((v4.y + v5.y) + (v6.y + v7.y));
    } else {
      const int s0 = slots[base + j + 0], s1 = slots[base + j + 1];
      const int s2 = slots[base + j + 2], s3 = slots[base + j + 3];
      const int s4 = slots[base + j + 4], s5 = slots[base + j + 5];
      const int s6 = slots[base + j + 6], s7 = slots[base + j + 7];
      const float v0 = hs[(long)s0 * 64 + lane];
      const float v1 = hs[(long)s1 * 64 + lane];
      const float v2 = hs[(long)s2 * 64 + lane];
      const float v3 = hs[(long)s3 * 64 + lane];
      const float v4 = hs[(long)s4 * 64 + lane];
      const float v5 = hs[(long)s5 * 64 + lane];
      const float v6 = hs[(long)s6 * 64 + lane];
      const float v7 = hs[(long)s7 * 64 + lane];
      ax += ((v0 + v1) + (v2 + v3)) + ((v4 + v5) + (v6 + v7));
    }
  }
  for (; j < deg; ++j) {
    const int s = slots[base + j];
    if (F == 128) {
      const float2 v = *reinterpret_cast<const float2*>(hs + (long)s * 128 + lane * 2);
      ax += v.x; ay += v.y;
    } else {
      ax += hs[(long)s * 64 + lane];
    }
  }

  const float di = dinv[wid];
  if (F == 128) {
    float2 r; r.x = ax * di; r.y = ay * di;
    *reinterpret_cast<float2*>(out + (long)wid * 128 + lane * 2) = r;
  } else {
    float v = ax * di;
    if (ADD_BIAS) v += bias[lane];
    out[(long)wid * 64 + lane] = v;
  }
}

// Sequential fixup for slot-overflow edges (expected count: 0).
// Single block of F threads; thread f owns target[d*F+f] -> plain RMW is safe.
template<int F>
__global__ void ovf_fix_k(const int2* __restrict__ ovf, const int* __restrict__ ovf_cnt,
                          const float* __restrict__ dinv, const float* __restrict__ hs,
                          float* __restrict__ target) {
  int m = *ovf_cnt; if (m > OVCAP) m = OVCAP;
  const int f = threadIdx.x;
  for (int i = 0; i < m; ++i) {
    const int s = ovf[i].x, d = ovf[i].y;
    target[(long)d * F + f] += hs[(long)s * F + f] * dinv[d];
  }
}

extern "C" void kernel_launch(void* const* d_in, const int* in_sizes, int n_in,
                              void* d_out, int out_size, void* d_ws, size_t ws_size,
                              hipStream_t stream) {
  const float* x  = (const float*)d_in[0];
  const float* W1 = (const float*)d_in[1];
  const float* b1 = (const float*)d_in[2];
  const float* W2 = (const float*)d_in[3];
  const float* b2 = (const float*)d_in[4];
  const int*   ei = (const int*)d_in[5];

  const int N = in_sizes[0] / IN_F;
  const int E = in_sizes[5] / 2;
  const int* src = ei;        // edge_index[0]
  const int* dst = ei + E;    // edge_index[1]
  float* out = (float*)d_out; // [N, 64]

  // workspace layout
  const int Npad = (N + 256) & ~255;
  int*   cnt     = (int*)d_ws;                        // N counters + ovf_cnt at cnt[N]
  int*   ovf_cnt = cnt + N;                           // 1
  int2*  ovf     = (int2*)(cnt + Npad);               // OVCAP pairs
  int*   slots   = (int*)(ovf + OVCAP);               // N*SLOT
  float* dinv    = (float*)(slots + (size_t)N * SLOT); // N
  float* hs1     = dinv + Npad;                       // N*128
  float* agg1    = hs1 + (size_t)N * HID_F;           // N*128
  float* hs2     = hs1;                               // reuse: dead after layer-1 gather

  const int B = 256;
  constexpr int NB = 8;

  // ---- binning (shared by both layers): one atomic pass, no scan ----
  zero_cnt_k<<<(N + 1 + B - 1) / B, B, 0, stream>>>(cnt, N + 1);
  fill_slot_k<<<(E + B - 1) / B, B, 0, stream>>>(src, dst, cnt, slots, ovf_cnt, ovf, E);
  dinv_k<<<(N + B - 1) / B, B, 0, stream>>>(cnt, dinv, N);

  // ---- layer 1 ----
  gemm_scale_k<IN_F, HID_F, NB, false>
      <<<(N + NB - 1) / NB, HID_F, 0, stream>>>(x, W1, nullptr, dinv, hs1, N);
  gather_slot_k<HID_F, false>
      <<<((size_t)N * 64 + B - 1) / B, B, 0, stream>>>(cnt, slots, dinv, hs1,
                                                       nullptr, agg1, N);
  ovf_fix_k<HID_F><<<1, HID_F, 0, stream>>>(ovf, ovf_cnt, dinv, hs1, agg1);

  // ---- layer 2 (b1+relu folded into GEMM load; b2 folded into gather store) ----
  gemm_scale_k<HID_F, OUT_F, NB, true>
      <<<(N + NB - 1) / NB, OUT_F, 0, stream>>>(agg1, W2, b1, dinv, hs2, N);
  gather_slot_k<OUT_F, true>
      <<<((size_t)N * 64 + B - 1) / B, B, 0, stream>>>(cnt, slots, dinv, hs2,
                                                       b2, out, N);
  ovf_fix_k<OUT_F><<<1, OUT_F, 0, stream>>>(ovf, ovf_cnt, dinv, hs2, out);
}

// Round 12
// 190.757 us; speedup vs baseline: 1.4421x; 1.0175x over previous
//
#include <hip/hip_runtime.h>

// GCN: out = Ahat( relu( Ahat(x@W1) + b1 ) @ W2 ) + b2,  Ahat = D^-1/2 (A+I) D^-1/2
// N=10000, E=640000, IN=128, HID=128, OUT=64.
// r3:  CSR gather formulation (no f32 atomics in hot path).
// r5:  8-deep MLP-batched gather (was latency-bound: VALUBusy 14%, VGPR=12).
// r9:  fixed-slot binning slots[d*128+pos] replaces count+scan+fill (236->194us).
// r11: fill_slot was the remaining measured hot spot class (44.9us, VALUBusy
//      0.33% = one atomic latency chain per thread). 4 edges/thread with int4
//      index loads + 4 independent atomics in flight. Also: dinv array/kernel
//      folded into consumers (1/sqrtf(cnt+1) on the fly); ovf_fix folded into
//      gather epilogue (wave owns its node -> race-free). Launches 9 -> 6.

static constexpr int IN_F  = 128;
static constexpr int HID_F = 128;
static constexpr int OUT_F = 64;
static constexpr int SLOT  = 128;   // slots per node
static constexpr int OVCAP = 4096;  // overflow list capacity

__global__ void zero_cnt_k(int* __restrict__ cnt, int total) {
  int i = blockIdx.x * blockDim.x + threadIdx.x;
  if (i < total) cnt[i] = 0;   // covers cnt[0..N) and ovf_cnt at cnt[N]
}

__device__ __forceinline__ void push_edge(int s, int d, int* cnt, int* slots,
                                          int* ovf_cnt, int2* ovf) {
  int pos = atomicAdd(&cnt[d], 1);
  if (pos < SLOT) {
    slots[(long)d * SLOT + pos] = s;
  } else {
    int op = atomicAdd(ovf_cnt, 1);
    if (op < OVCAP) ovf[op] = make_int2(s, d);
  }
}

// 4 edges per thread: int4 index loads, 4 independent atomics in flight.
__global__ void fill_slot_k(const int* __restrict__ src, const int* __restrict__ dst,
                            int* __restrict__ cnt, int* __restrict__ slots,
                            int* __restrict__ ovf_cnt, int2* __restrict__ ovf, int E) {
  const int t  = blockIdx.x * blockDim.x + threadIdx.x;
  const int e0 = t * 4;
  if (e0 >= E) return;
  if (((E & 3) == 0) && (e0 + 4 <= E)) {
    const int4 s4 = *reinterpret_cast<const int4*>(src + e0);
    const int4 d4 = *reinterpret_cast<const int4*>(dst + e0);
    // 4 independent atomics issue back-to-back (compiler waits once for all)
    const int p0 = atomicAdd(&cnt[d4.x], 1);
    const int p1 = atomicAdd(&cnt[d4.y], 1);
    const int p2 = atomicAdd(&cnt[d4.z], 1);
    const int p3 = atomicAdd(&cnt[d4.w], 1);
    if (p0 < SLOT) slots[(long)d4.x * SLOT + p0] = s4.x;
    else { int op = atomicAdd(ovf_cnt, 1); if (op < OVCAP) ovf[op] = make_int2(s4.x, d4.x); }
    if (p1 < SLOT) slots[(long)d4.y * SLOT + p1] = s4.y;
    else { int op = atomicAdd(ovf_cnt, 1); if (op < OVCAP) ovf[op] = make_int2(s4.y, d4.y); }
    if (p2 < SLOT) slots[(long)d4.z * SLOT + p2] = s4.z;
    else { int op = atomicAdd(ovf_cnt, 1); if (op < OVCAP) ovf[op] = make_int2(s4.z, d4.z); }
    if (p3 < SLOT) slots[(long)d4.w * SLOT + p3] = s4.w;
    else { int op = atomicAdd(ovf_cnt, 1); if (op < OVCAP) ovf[op] = make_int2(s4.w, d4.w); }
  } else {
    const int e1 = min(e0 + 4, E);
    for (int e = e0; e < e1; ++e) push_edge(src[e], dst[e], cnt, slots, ovf_cnt, ovf);
  }
}

// hs[n][f] = (sum_k in'[n][k] * W[k][f]) / sqrt(cnt[n]+1)   (pre-scaled by src side)
// in'[n][k] = RELU_BIAS ? relu(in[n][k] + bin[k]) : in[n][k]
template<int K, int F, int NB, bool RELU_BIAS>
__global__ __launch_bounds__(F) void gemm_scale_k(
    const float* __restrict__ in, const float* __restrict__ W,
    const float* __restrict__ bin, const int* __restrict__ cnt,
    float* __restrict__ hs, int N) {
  __shared__ float xs[NB][K];
  const int f  = threadIdx.x;
  const int n0 = blockIdx.x * NB;

  for (int i = 0; i < NB; ++i) {
    int n = n0 + i;
    for (int k = f; k < K; k += F) {
      float v = (n < N) ? in[(long)n * K + k] : 0.0f;
      if (RELU_BIAS) v = fmaxf(v + bin[k], 0.0f);
      xs[i][k] = v;
    }
  }
  __syncthreads();

  float acc[NB];
#pragma unroll
  for (int i = 0; i < NB; ++i) acc[i] = 0.0f;

  for (int k = 0; k < K; ++k) {
    float w = W[k * F + f];
#pragma unroll
    for (int i = 0; i < NB; ++i) acc[i] = fmaf(xs[i][k], w, acc[i]);
  }

  for (int i = 0; i < NB; ++i) {
    int n = n0 + i;
    if (n < N) {
      const float di = 1.0f / sqrtf((float)(cnt[n] + 1));
      hs[(long)n * F + f] = acc[i] * di;
    }
  }
}

// One wave per node: out[n] = dinv[n] * (hs[n] + sum_{slots} hs[src] + sum_{ovf:d==n} hs[src]) [+ bias]
// 8-deep MLP-batched inner loop (r5); slot-row indexing (r9); ovf folded (r11).
template<int F, bool ADD_BIAS>
__global__ __launch_bounds__(256) void gather_slot_k(
    const int* __restrict__ cnt, const int* __restrict__ slots,
    const int* __restrict__ ovf_cnt, const int2* __restrict__ ovf,
    const float* __restrict__ hs, const float* __restrict__ bias,
    float* __restrict__ out, int N) {
  const int wid  = (int)((blockIdx.x * blockDim.x + threadIdx.x) >> 6);
  const int lane = threadIdx.x & 63;
  if (wid >= N) return;
  const int craw = __builtin_amdgcn_readfirstlane(cnt[wid]);
  const int deg  = min(craw, SLOT);
  const long base = (long)wid * SLOT;

  float ax, ay;
  if (F == 128) {
    const float2 v = *reinterpret_cast<const float2*>(hs + (long)wid * 128 + lane * 2);
    ax = v.x; ay = v.y;
  } else {
    ax = hs[(long)wid * 64 + lane]; ay = 0.0f;
  }

  int j = 0;
  for (; j + 8 <= deg; j += 8) {
    if (F == 128) {
      float2 v0, v1, v2, v3, v4, v5, v6, v7;
      {
        const int s0 = slots[base + j + 0], s1 = slots[base + j + 1];
        const int s2 = slots[base + j + 2], s3 = slots[base + j + 3];
        const int s4 = slots[base + j + 4], s5 = slots[base + j + 5];
        const int s6 = slots[base + j + 6], s7 = slots[base + j + 7];
        const long o = lane * 2;
        v0 = *reinterpret_cast<const float2*>(hs + (long)s0 * 128 + o);
        v1 = *reinterpret_cast<const float2*>(hs + (long)s1 * 128 + o);
        v2 = *reinterpret_cast<const float2*>(hs + (long)s2 * 128 + o);
        v3 = *reinterpret_cast<const float2*>(hs + (long)s3 * 128 + o);
        v4 = *reinterpret_cast<const float2*>(hs + (long)s4 * 128 + o);
        v5 = *reinterpret_cast<const float2*>(hs + (long)s5 * 128 + o);
        v6 = *reinterpret_cast<const float2*>(hs + (long)s6 * 128 + o);
        v7 = *reinterpret_cast<const float2*>(hs + (long)s7 * 128 + o);
      }
      ax += ((v0.x + v1.x) + (v2.x + v3.x)) + ((v4.x + v5.x) + (v6.x + v7.x));
      ay += ((v0.y + v1.y) + (v2.y + v3.y)) + ((v4.y + v5.y) + (v6.y + v7.y));
    } else {
      const int s0 = slots[base + j + 0], s1 = slots[base + j + 1];
      const int s2 = slots[base + j + 2], s3 = slots[base + j + 3];
      const int s4 = slots[base + j + 4], s5 = slots[base + j + 5];
      const int s6 = slots[base + j + 6], s7 = slots[base + j + 7];
      const float v0 = hs[(long)s0 * 64 + lane];
      const float v1 = hs[(long)s1 * 64 + lane];
      const float v2 = hs[(long)s2 * 64 + lane];
      const float v3 = hs[(long)s3 * 64 + lane];
      const float v4 = hs[(long)s4 * 64 + lane];
      const float v5 = hs[(long)s5 * 64 + lane];
      const float v6 = hs[(long)s6 * 64 + lane];
      const float v7 = hs[(long)s7 * 64 + lane];
      ax += ((v0 + v1) + (v2 + v3)) + ((v4 + v5) + (v6 + v7));
    }
  }
  for (; j < deg; ++j) {
    const int s = slots[base + j];
    if (F == 128) {
      const float2 v = *reinterpret_cast<const float2*>(hs + (long)s * 128 + lane * 2);
      ax += v.x; ay += v.y;
    } else {
      ax += hs[(long)s * 64 + lane];
    }
  }

  // overflow fold (expected empty; one scalar load + skipped loop)
  {
    int m = __builtin_amdgcn_readfirstlane(*ovf_cnt);
    m = min(m, OVCAP);
    for (int i = 0; i < m; ++i) {
      const int2 p = ovf[i];
      if (p.y == wid) {
        if (F == 128) {
          const float2 v = *reinterpret_cast<const float2*>(hs + (long)p.x * 128 + lane * 2);
          ax += v.x; ay += v.y;
        } else {
          ax += hs[(long)p.x * 64 + lane];
        }
      }
    }
  }

  const float di = 1.0f / sqrtf((float)(craw + 1));
  if (F == 128) {
    float2 r; r.x = ax * di; r.y = ay * di;
    *reinterpret_cast<float2*>(out + (long)wid * 128 + lane * 2) = r;
  } else {
    float v = ax * di;
    if (ADD_BIAS) v += bias[lane];
    out[(long)wid * 64 + lane] = v;
  }
}

extern "C" void kernel_launch(void* const* d_in, const int* in_sizes, int n_in,
                              void* d_out, int out_size, void* d_ws, size_t ws_size,
                              hipStream_t stream) {
  const float* x  = (const float*)d_in[0];
  const float* W1 = (const float*)d_in[1];
  const float* b1 = (const float*)d_in[2];
  const float* W2 = (const float*)d_in[3];
  const float* b2 = (const float*)d_in[4];
  const int*   ei = (const int*)d_in[5];

  const int N = in_sizes[0] / IN_F;
  const int E = in_sizes[5] / 2;
  const int* src = ei;        // edge_index[0]
  const int* dst = ei + E;    // edge_index[1]
  float* out = (float*)d_out; // [N, 64]

  // workspace layout
  const int Npad = (N + 256) & ~255;
  int*   cnt     = (int*)d_ws;                         // N counters + ovf_cnt at cnt[N]
  int*   ovf_cnt = cnt + N;                            // 1
  int2*  ovf     = (int2*)(cnt + Npad);                // OVCAP pairs
  int*   slots   = (int*)(ovf + OVCAP);                // N*SLOT
  float* hs1     = (float*)(slots + (size_t)N * SLOT); // N*128
  float* agg1    = hs1 + (size_t)N * HID_F;            // N*128
  float* hs2     = hs1;                                // reuse: dead after layer-1 gather

  const int B = 256;
  constexpr int NB = 8;

  // ---- binning (shared by both layers): one atomic pass, 4 edges/thread ----
  zero_cnt_k<<<(N + 1 + B - 1) / B, B, 0, stream>>>(cnt, N + 1);
  fill_slot_k<<<((E + 3) / 4 + B - 1) / B, B, 0, stream>>>(src, dst, cnt, slots,
                                                           ovf_cnt, ovf, E);

  // ---- layer 1 ----
  gemm_scale_k<IN_F, HID_F, NB, false>
      <<<(N + NB - 1) / NB, HID_F, 0, stream>>>(x, W1, nullptr, cnt, hs1, N);
  gather_slot_k<HID_F, false>
      <<<((size_t)N * 64 + B - 1) / B, B, 0, stream>>>(cnt, slots, ovf_cnt, ovf,
                                                       hs1, nullptr, agg1, N);

  // ---- layer 2 (b1+relu folded into GEMM load; b2 folded into gather store) ----
  gemm_scale_k<HID_F, OUT_F, NB, true>
      <<<(N + NB - 1) / NB, OUT_F, 0, stream>>>(agg1, W2, b1, cnt, hs2, N);
  gather_slot_k<OUT_F, true>
      <<<((size_t)N * 64 + B - 1) / B, B, 0, stream>>>(cnt, slots, ovf_cnt, ovf,
                                                       hs2, b2, out, N);
}

// Round 14
// 190.094 us; speedup vs baseline: 1.4471x; 1.0035x over previous
//
#include <hip/hip_runtime.h>

// GCN: out = Ahat( relu( Ahat(x@W1) + b1 ) @ W2 ) + b2,  Ahat = D^-1/2 (A+I) D^-1/2
// N=10000, E=640000, IN=128, HID=128, OUT=64.
// r3:  CSR gather formulation (no f32 atomics in hot path).
// r5:  8-deep MLP-batched gather (latency-bound: VALUBusy 14%, VGPR=12).
// r9:  fixed-slot binning slots[d*128+pos] replaces count+scan+fill (236->194us).
// r11: 4-edge/thread fill batching -> NULL => fill pinned by memory-system
//      (cross-XCD line ping-pong on scattered 4B writes; 35MB HBM WRITE_SIZE).
// r12: folded dinv/ovf into consumers; 194->190.8us.
// r13: fp16 hs: -16.5us BUT failed post-timing absmax (3.9e-3 vs 3.4e-3
//      threshold; fp16 eps x 65-term sums x max-statistic + atomic-order
//      variation straddles the gate). REVERTED to f32 for good.
// r14: single new change vs r12: GEMM k-loop #pragma unroll 8 — breaks the
//      128-long serial L2-latency chain on w = W[k*F+f] (W1=64KB > L1).

static constexpr int IN_F  = 128;
static constexpr int HID_F = 128;
static constexpr int OUT_F = 64;
static constexpr int SLOT  = 128;   // slots per node
static constexpr int OVCAP = 4096;  // overflow list capacity

__global__ void zero_cnt_k(int* __restrict__ cnt, int total) {
  int i = blockIdx.x * blockDim.x + threadIdx.x;
  if (i < total) cnt[i] = 0;   // covers cnt[0..N) and ovf_cnt at cnt[N]
}

__device__ __forceinline__ void push_edge(int s, int d, int* cnt, int* slots,
                                          int* ovf_cnt, int2* ovf) {
  int pos = atomicAdd(&cnt[d], 1);
  if (pos < SLOT) {
    slots[(long)d * SLOT + pos] = s;
  } else {
    int op = atomicAdd(ovf_cnt, 1);
    if (op < OVCAP) ovf[op] = make_int2(s, d);
  }
}

// UNCHANGED (control): pinned at ~43.5us by memory-system throughput.
__global__ void fill_slot_k(const int* __restrict__ src, const int* __restrict__ dst,
                            int* __restrict__ cnt, int* __restrict__ slots,
                            int* __restrict__ ovf_cnt, int2* __restrict__ ovf, int E) {
  const int t  = blockIdx.x * blockDim.x + threadIdx.x;
  const int e0 = t * 4;
  if (e0 >= E) return;
  if (((E & 3) == 0) && (e0 + 4 <= E)) {
    const int4 s4 = *reinterpret_cast<const int4*>(src + e0);
    const int4 d4 = *reinterpret_cast<const int4*>(dst + e0);
    const int p0 = atomicAdd(&cnt[d4.x], 1);
    const int p1 = atomicAdd(&cnt[d4.y], 1);
    const int p2 = atomicAdd(&cnt[d4.z], 1);
    const int p3 = atomicAdd(&cnt[d4.w], 1);
    if (p0 < SLOT) slots[(long)d4.x * SLOT + p0] = s4.x;
    else { int op = atomicAdd(ovf_cnt, 1); if (op < OVCAP) ovf[op] = make_int2(s4.x, d4.x); }
    if (p1 < SLOT) slots[(long)d4.y * SLOT + p1] = s4.y;
    else { int op = atomicAdd(ovf_cnt, 1); if (op < OVCAP) ovf[op] = make_int2(s4.y, d4.y); }
    if (p2 < SLOT) slots[(long)d4.z * SLOT + p2] = s4.z;
    else { int op = atomicAdd(ovf_cnt, 1); if (op < OVCAP) ovf[op] = make_int2(s4.z, d4.z); }
    if (p3 < SLOT) slots[(long)d4.w * SLOT + p3] = s4.w;
    else { int op = atomicAdd(ovf_cnt, 1); if (op < OVCAP) ovf[op] = make_int2(s4.w, d4.w); }
  } else {
    const int e1 = min(e0 + 4, E);
    for (int e = e0; e < e1; ++e) push_edge(src[e], dst[e], cnt, slots, ovf_cnt, ovf);
  }
}

// hs[n][f] = (sum_k in'[n][k] * W[k][f]) / sqrt(cnt[n]+1)
// in'[n][k] = RELU_BIAS ? relu(in[n][k] + bin[k]) : in[n][k]
// r14: k-loop unrolled 8x -> 8 independent W loads in flight.
template<int K, int F, int NB, bool RELU_BIAS>
__global__ __launch_bounds__(F) void gemm_scale_k(
    const float* __restrict__ in, const float* __restrict__ W,
    const float* __restrict__ bin, const int* __restrict__ cnt,
    float* __restrict__ hs, int N) {
  __shared__ float xs[NB][K];
  const int f  = threadIdx.x;
  const int n0 = blockIdx.x * NB;

  for (int i = 0; i < NB; ++i) {
    int n = n0 + i;
    for (int k = f; k < K; k += F) {
      float v = (n < N) ? in[(long)n * K + k] : 0.0f;
      if (RELU_BIAS) v = fmaxf(v + bin[k], 0.0f);
      xs[i][k] = v;
    }
  }
  __syncthreads();

  float acc[NB];
#pragma unroll
  for (int i = 0; i < NB; ++i) acc[i] = 0.0f;

#pragma unroll 8
  for (int k = 0; k < K; ++k) {
    float w = W[k * F + f];
#pragma unroll
    for (int i = 0; i < NB; ++i) acc[i] = fmaf(xs[i][k], w, acc[i]);
  }

  for (int i = 0; i < NB; ++i) {
    int n = n0 + i;
    if (n < N) {
      const float di = 1.0f / sqrtf((float)(cnt[n] + 1));
      hs[(long)n * F + f] = acc[i] * di;
    }
  }
}

// One wave per node: out[n] = dinv[n]*(hs[n] + sum_slots hs[src] + ovf) [+ bias]
// EXACT r12 structure (f32, 8-deep MLP batch, ovf folded).
template<int F, bool ADD_BIAS>
__global__ __launch_bounds__(256) void gather_slot_k(
    const int* __restrict__ cnt, const int* __restrict__ slots,
    const int* __restrict__ ovf_cnt, const int2* __restrict__ ovf,
    const float* __restrict__ hs, const float* __restrict__ bias,
    float* __restrict__ out, int N) {
  const int wid  = (int)((blockIdx.x * blockDim.x + threadIdx.x) >> 6);
  const int lane = threadIdx.x & 63;
  if (wid >= N) return;
  const int craw = __builtin_amdgcn_readfirstlane(cnt[wid]);
  const int deg  = min(craw, SLOT);
  const long base = (long)wid * SLOT;

  float ax, ay = 0.0f;
  if (F == 128) {
    const float2 v = *reinterpret_cast<const float2*>(hs + (long)wid * 128 + lane * 2);
    ax = v.x; ay = v.y;
  } else {
    ax = hs[(long)wid * 64 + lane];
  }

  int j = 0;
  for (; j + 8 <= deg; j += 8) {
    if (F == 128) {
      float2 v0, v1, v2, v3, v4, v5, v6, v7;
      {
        const int s0 = slots[base + j + 0], s1 = slots[base + j + 1];
        const int s2 = slots[base + j + 2], s3 = slots[base + j + 3];
        const int s4 = slots[base + j + 4], s5 = slots[base + j + 5];
        const int s6 = slots[base + j + 6], s7 = slots[base + j + 7];
        const long o = lane * 2;
        v0 = *reinterpret_cast<const float2*>(hs + (long)s0 * 128 + o);
        v1 = *reinterpret_cast<const float2*>(hs + (long)s1 * 128 + o);
        v2 = *reinterpret_cast<const float2*>(hs + (long)s2 * 128 + o);
        v3 = *reinterpret_cast<const float2*>(hs + (long)s3 * 128 + o);
        v4 = *reinterpret_cast<const float2*>(hs + (long)s4 * 128 + o);
        v5 = *reinterpret_cast<const float2*>(hs + (long)s5 * 128 + o);
        v6 = *reinterpret_cast<const float2*>(hs + (long)s6 * 128 + o);
        v7 = *reinterpret_cast<const float2*>(hs + (long)s7 * 128 + o);
      }
      ax += ((v0.x + v1.x) + (v2.x + v3.x)) + ((v4.x + v5.x) + (v6.x + v7.x));
      ay += ((v0.y + v1.y) + (v2.y + v3.y)) + ((v4.y + v5.y) + (v6.y + v7.y));
    } else {
      const int s0 = slots[base + j + 0], s1 = slots[base + j + 1];
      const int s2 = slots[base + j + 2], s3 = slots[base + j + 3];
      const int s4 = slots[base + j + 4], s5 = slots[base + j + 5];
      const int s6 = slots[base + j + 6], s7 = slots[base + j + 7];
      const float v0 = hs[(long)s0 * 64 + lane];
      const float v1 = hs[(long)s1 * 64 + lane];
      const float v2 = hs[(long)s2 * 64 + lane];
      const float v3 = hs[(long)s3 * 64 + lane];
      const float v4 = hs[(long)s4 * 64 + lane];
      const float v5 = hs[(long)s5 * 64 + lane];
      const float v6 = hs[(long)s6 * 64 + lane];
      const float v7 = hs[(long)s7 * 64 + lane];
      ax += ((v0 + v1) + (v2 + v3)) + ((v4 + v5) + (v6 + v7));
    }
  }
  for (; j < deg; ++j) {
    const int s = slots[base + j];
    if (F == 128) {
      const float2 v = *reinterpret_cast<const float2*>(hs + (long)s * 128 + lane * 2);
      ax += v.x; ay += v.y;
    } else {
      ax += hs[(long)s * 64 + lane];
    }
  }

  // overflow fold (expected empty; one scalar load + skipped loop)
  {
    int m = __builtin_amdgcn_readfirstlane(*ovf_cnt);
    m = min(m, OVCAP);
    for (int i = 0; i < m; ++i) {
      const int2 p = ovf[i];
      if (p.y == wid) {
        if (F == 128) {
          const float2 v = *reinterpret_cast<const float2*>(hs + (long)p.x * 128 + lane * 2);
          ax += v.x; ay += v.y;
        } else {
          ax += hs[(long)p.x * 64 + lane];
        }
      }
    }
  }

  const float di = 1.0f / sqrtf((float)(craw + 1));
  if (F == 128) {
    float2 r; r.x = ax * di; r.y = ay * di;
    *reinterpret_cast<float2*>(out + (long)wid * 128 + lane * 2) = r;
  } else {
    float v = ax * di;
    if (ADD_BIAS) v += bias[lane];
    out[(long)wid * 64 + lane] = v;
  }
}

extern "C" void kernel_launch(void* const* d_in, const int* in_sizes, int n_in,
                              void* d_out, int out_size, void* d_ws, size_t ws_size,
                              hipStream_t stream) {
  const float* x  = (const float*)d_in[0];
  const float* W1 = (const float*)d_in[1];
  const float* b1 = (const float*)d_in[2];
  const float* W2 = (const float*)d_in[3];
  const float* b2 = (const float*)d_in[4];
  const int*   ei = (const int*)d_in[5];

  const int N = in_sizes[0] / IN_F;
  const int E = in_sizes[5] / 2;
  const int* src = ei;        // edge_index[0]
  const int* dst = ei + E;    // edge_index[1]
  float* out = (float*)d_out; // [N, 64]

  // workspace layout
  const int Npad = (N + 256) & ~255;
  int*   cnt     = (int*)d_ws;                         // N counters + ovf_cnt at cnt[N]
  int*   ovf_cnt = cnt + N;                            // 1
  int2*  ovf     = (int2*)(cnt + Npad);                // OVCAP pairs
  int*   slots   = (int*)(ovf + OVCAP);                // N*SLOT ints
  float* hs1     = (float*)(slots + (size_t)N * SLOT); // N*128 floats
  float* agg1    = hs1 + (size_t)N * HID_F;            // N*128 floats
  float* hs2     = hs1;                                // reuse: dead after gather-1

  const int B = 256;
  constexpr int NB = 8;

  // ---- binning (shared by both layers) ----
  zero_cnt_k<<<(N + 1 + B - 1) / B, B, 0, stream>>>(cnt, N + 1);
  fill_slot_k<<<((E + 3) / 4 + B - 1) / B, B, 0, stream>>>(src, dst, cnt, slots,
                                                           ovf_cnt, ovf, E);

  // ---- layer 1 ----
  gemm_scale_k<IN_F, HID_F, NB, false>
      <<<(N + NB - 1) / NB, HID_F, 0, stream>>>(x, W1, nullptr, cnt, hs1, N);
  gather_slot_k<HID_F, false>
      <<<((size_t)N * 64 + B - 1) / B, B, 0, stream>>>(cnt, slots, ovf_cnt, ovf,
                                                       hs1, nullptr, agg1, N);

  // ---- layer 2 (b1+relu folded into GEMM load; b2 folded into gather store) ----
  gemm_scale_k<HID_F, OUT_F, NB, true>
      <<<(N + NB - 1) / NB, OUT_F, 0, stream>>>(agg1, W2, b1, cnt, hs2, N);
  gather_slot_k<OUT_F, true>
      <<<((size_t)N * 64 + B - 1) / B, B, 0, stream>>>(cnt, slots, ovf_cnt, ovf,
                                                       hs2, b2, out, N);
}

// Round 15
// 186.627 us; speedup vs baseline: 1.4740x; 1.0186x over previous
//
#include <hip/hip_runtime.h>

// GCN: out = Ahat( relu( Ahat(x@W1) + b1 ) @ W2 ) + b2,  Ahat = D^-1/2 (A+I) D^-1/2
// N=10000, E=640000, IN=128, HID=128, OUT=64.
// r3:  CSR gather formulation (no f32 atomics in hot path).
// r5:  8-deep MLP-batched gather (latency-bound: VALUBusy 14%, VGPR=12).
// r9:  fixed-slot binning slots[d*128+pos] replaces count+scan+fill (236->194us).
// r11: 4-edge/thread fill batching -> NULL => fill pinned by memory-system.
// r12: folded dinv/ovf into consumers; 194->190.8us.
// r13: fp16 hs + depth16 bundle: -16.5us but FAILED post-timing absmax gate
//      (fp16 reverted for good; depth16 never isolated).
// r14: GEMM k-loop unroll 8 -> NULL (190.1us) => GEMMs not the pot.
// r15: isolate r13's depth component: gather batch 8 -> 16 (f32). Also
//      zero_cnt_k -> hipMemsetAsync (one less launch). Pre-committed read:
//      -8..15us => still latency-slack; null => L2-request-throughput-bound
//      and next lever must cut cache-line requests (split-plane hs) not MLP.

static constexpr int IN_F  = 128;
static constexpr int HID_F = 128;
static constexpr int OUT_F = 64;
static constexpr int SLOT  = 128;   // slots per node
static constexpr int OVCAP = 4096;  // overflow list capacity

__device__ __forceinline__ void push_edge(int s, int d, int* cnt, int* slots,
                                          int* ovf_cnt, int2* ovf) {
  int pos = atomicAdd(&cnt[d], 1);
  if (pos < SLOT) {
    slots[(long)d * SLOT + pos] = s;
  } else {
    int op = atomicAdd(ovf_cnt, 1);
    if (op < OVCAP) ovf[op] = make_int2(s, d);
  }
}

// UNCHANGED (control): pinned at ~43.5us by memory-system throughput.
__global__ void fill_slot_k(const int* __restrict__ src, const int* __restrict__ dst,
                            int* __restrict__ cnt, int* __restrict__ slots,
                            int* __restrict__ ovf_cnt, int2* __restrict__ ovf, int E) {
  const int t  = blockIdx.x * blockDim.x + threadIdx.x;
  const int e0 = t * 4;
  if (e0 >= E) return;
  if (((E & 3) == 0) && (e0 + 4 <= E)) {
    const int4 s4 = *reinterpret_cast<const int4*>(src + e0);
    const int4 d4 = *reinterpret_cast<const int4*>(dst + e0);
    const int p0 = atomicAdd(&cnt[d4.x], 1);
    const int p1 = atomicAdd(&cnt[d4.y], 1);
    const int p2 = atomicAdd(&cnt[d4.z], 1);
    const int p3 = atomicAdd(&cnt[d4.w], 1);
    if (p0 < SLOT) slots[(long)d4.x * SLOT + p0] = s4.x;
    else { int op = atomicAdd(ovf_cnt, 1); if (op < OVCAP) ovf[op] = make_int2(s4.x, d4.x); }
    if (p1 < SLOT) slots[(long)d4.y * SLOT + p1] = s4.y;
    else { int op = atomicAdd(ovf_cnt, 1); if (op < OVCAP) ovf[op] = make_int2(s4.y, d4.y); }
    if (p2 < SLOT) slots[(long)d4.z * SLOT + p2] = s4.z;
    else { int op = atomicAdd(ovf_cnt, 1); if (op < OVCAP) ovf[op] = make_int2(s4.z, d4.z); }
    if (p3 < SLOT) slots[(long)d4.w * SLOT + p3] = s4.w;
    else { int op = atomicAdd(ovf_cnt, 1); if (op < OVCAP) ovf[op] = make_int2(s4.w, d4.w); }
  } else {
    const int e1 = min(e0 + 4, E);
    for (int e = e0; e < e1; ++e) push_edge(src[e], dst[e], cnt, slots, ovf_cnt, ovf);
  }
}

// hs[n][f] = (sum_k in'[n][k] * W[k][f]) / sqrt(cnt[n]+1)
// in'[n][k] = RELU_BIAS ? relu(in[n][k] + bin[k]) : in[n][k]
template<int K, int F, int NB, bool RELU_BIAS>
__global__ __launch_bounds__(F) void gemm_scale_k(
    const float* __restrict__ in, const float* __restrict__ W,
    const float* __restrict__ bin, const int* __restrict__ cnt,
    float* __restrict__ hs, int N) {
  __shared__ float xs[NB][K];
  const int f  = threadIdx.x;
  const int n0 = blockIdx.x * NB;

  for (int i = 0; i < NB; ++i) {
    int n = n0 + i;
    for (int k = f; k < K; k += F) {
      float v = (n < N) ? in[(long)n * K + k] : 0.0f;
      if (RELU_BIAS) v = fmaxf(v + bin[k], 0.0f);
      xs[i][k] = v;
    }
  }
  __syncthreads();

  float acc[NB];
#pragma unroll
  for (int i = 0; i < NB; ++i) acc[i] = 0.0f;

#pragma unroll 8
  for (int k = 0; k < K; ++k) {
    float w = W[k * F + f];
#pragma unroll
    for (int i = 0; i < NB; ++i) acc[i] = fmaf(xs[i][k], w, acc[i]);
  }

  for (int i = 0; i < NB; ++i) {
    int n = n0 + i;
    if (n < N) {
      const float di = 1.0f / sqrtf((float)(cnt[n] + 1));
      hs[(long)n * F + f] = acc[i] * di;
    }
  }
}

// One wave per node: out[n] = dinv[n]*(hs[n] + sum_slots hs[src] + ovf) [+ bias]
// r15: 16-deep MLP batch (f32), fully-unrolled static indexing.
template<int F, bool ADD_BIAS>
__global__ __launch_bounds__(256) void gather_slot_k(
    const int* __restrict__ cnt, const int* __restrict__ slots,
    const int* __restrict__ ovf_cnt, const int2* __restrict__ ovf,
    const float* __restrict__ hs, const float* __restrict__ bias,
    float* __restrict__ out, int N) {
  const int wid  = (int)((blockIdx.x * blockDim.x + threadIdx.x) >> 6);
  const int lane = threadIdx.x & 63;
  if (wid >= N) return;
  const int craw = __builtin_amdgcn_readfirstlane(cnt[wid]);
  const int deg  = min(craw, SLOT);
  const long base = (long)wid * SLOT;

  float ax, ay = 0.0f;
  if (F == 128) {
    const float2 v = *reinterpret_cast<const float2*>(hs + (long)wid * 128 + lane * 2);
    ax = v.x; ay = v.y;
  } else {
    ax = hs[(long)wid * 64 + lane];
  }

  int j = 0;
  for (; j + 16 <= deg; j += 16) {
    int sv[16];
#pragma unroll
    for (int u = 0; u < 16; ++u) sv[u] = slots[base + j + u];
    if (F == 128) {
      float2 hv[16];
#pragma unroll
      for (int u = 0; u < 16; ++u)
        hv[u] = *reinterpret_cast<const float2*>(hs + (long)sv[u] * 128 + lane * 2);
      float sx0 = 0.f, sy0 = 0.f, sx1 = 0.f, sy1 = 0.f;
#pragma unroll
      for (int u = 0; u < 16; u += 2) {
        sx0 += hv[u].x;     sy0 += hv[u].y;
        sx1 += hv[u + 1].x; sy1 += hv[u + 1].y;
      }
      ax += sx0 + sx1; ay += sy0 + sy1;
    } else {
      float hv[16];
#pragma unroll
      for (int u = 0; u < 16; ++u) hv[u] = hs[(long)sv[u] * 64 + lane];
      float s0 = 0.f, s1 = 0.f;
#pragma unroll
      for (int u = 0; u < 16; u += 2) { s0 += hv[u]; s1 += hv[u + 1]; }
      ax += s0 + s1;
    }
  }
  for (; j + 4 <= deg; j += 4) {
    int sv[4];
#pragma unroll
    for (int u = 0; u < 4; ++u) sv[u] = slots[base + j + u];
    if (F == 128) {
      float2 hv[4];
#pragma unroll
      for (int u = 0; u < 4; ++u)
        hv[u] = *reinterpret_cast<const float2*>(hs + (long)sv[u] * 128 + lane * 2);
#pragma unroll
      for (int u = 0; u < 4; ++u) { ax += hv[u].x; ay += hv[u].y; }
    } else {
      float hv[4];
#pragma unroll
      for (int u = 0; u < 4; ++u) hv[u] = hs[(long)sv[u] * 64 + lane];
#pragma unroll
      for (int u = 0; u < 4; ++u) ax += hv[u];
    }
  }
  for (; j < deg; ++j) {
    const int s = slots[base + j];
    if (F == 128) {
      const float2 v = *reinterpret_cast<const float2*>(hs + (long)s * 128 + lane * 2);
      ax += v.x; ay += v.y;
    } else {
      ax += hs[(long)s * 64 + lane];
    }
  }

  // overflow fold (expected empty; one scalar load + skipped loop)
  {
    int m = __builtin_amdgcn_readfirstlane(*ovf_cnt);
    m = min(m, OVCAP);
    for (int i = 0; i < m; ++i) {
      const int2 p = ovf[i];
      if (p.y == wid) {
        if (F == 128) {
          const float2 v = *reinterpret_cast<const float2*>(hs + (long)p.x * 128 + lane * 2);
          ax += v.x; ay += v.y;
        } else {
          ax += hs[(long)p.x * 64 + lane];
        }
      }
    }
  }

  const float di = 1.0f / sqrtf((float)(craw + 1));
  if (F == 128) {
    float2 r; r.x = ax * di; r.y = ay * di;
    *reinterpret_cast<float2*>(out + (long)wid * 128 + lane * 2) = r;
  } else {
    float v = ax * di;
    if (ADD_BIAS) v += bias[lane];
    out[(long)wid * 64 + lane] = v;
  }
}

extern "C" void kernel_launch(void* const* d_in, const int* in_sizes, int n_in,
                              void* d_out, int out_size, void* d_ws, size_t ws_size,
                              hipStream_t stream) {
  const float* x  = (const float*)d_in[0];
  const float* W1 = (const float*)d_in[1];
  const float* b1 = (const float*)d_in[2];
  const float* W2 = (const float*)d_in[3];
  const float* b2 = (const float*)d_in[4];
  const int*   ei = (const int*)d_in[5];

  const int N = in_sizes[0] / IN_F;
  const int E = in_sizes[5] / 2;
  const int* src = ei;        // edge_index[0]
  const int* dst = ei + E;    // edge_index[1]
  float* out = (float*)d_out; // [N, 64]

  // workspace layout
  const int Npad = (N + 256) & ~255;
  int*   cnt     = (int*)d_ws;                         // N counters + ovf_cnt at cnt[N]
  int*   ovf_cnt = cnt + N;                            // 1 (contiguous with cnt)
  int2*  ovf     = (int2*)(cnt + Npad);                // OVCAP pairs
  int*   slots   = (int*)(ovf + OVCAP);                // N*SLOT ints
  float* hs1     = (float*)(slots + (size_t)N * SLOT); // N*128 floats
  float* agg1    = hs1 + (size_t)N * HID_F;            // N*128 floats
  float* hs2     = hs1;                                // reuse: dead after gather-1

  const int B = 256;
  constexpr int NB = 8;

  // ---- binning (shared by both layers) ----
  hipMemsetAsync(cnt, 0, (size_t)(N + 1) * sizeof(int), stream);  // cnt + ovf_cnt
  fill_slot_k<<<((E + 3) / 4 + B - 1) / B, B, 0, stream>>>(src, dst, cnt, slots,
                                                           ovf_cnt, ovf, E);

  // ---- layer 1 ----
  gemm_scale_k<IN_F, HID_F, NB, false>
      <<<(N + NB - 1) / NB, HID_F, 0, stream>>>(x, W1, nullptr, cnt, hs1, N);
  gather_slot_k<HID_F, false>
      <<<((size_t)N * 64 + B - 1) / B, B, 0, stream>>>(cnt, slots, ovf_cnt, ovf,
                                                       hs1, nullptr, agg1, N);

  // ---- layer 2 (b1+relu folded into GEMM load; b2 folded into gather store) ----
  gemm_scale_k<HID_F, OUT_F, NB, true>
      <<<(N + NB - 1) / NB, OUT_F, 0, stream>>>(agg1, W2, b1, cnt, hs2, N);
  gather_slot_k<OUT_F, true>
      <<<((size_t)N * 64 + B - 1) / B, B, 0, stream>>>(cnt, slots, ovf_cnt, ovf,
                                                       hs2, b2, out, N);
}